// Round 1
// baseline (865.232 us; speedup 1.0000x reference)
//
#include <hip/hip_runtime.h>

#ifndef MIN
#define MIN(a,b) ((a)<(b)?(a):(b))
#endif

// ---------------------------------------------------------------------------
// CSR build kernels
// ---------------------------------------------------------------------------

__global__ void count_kernel(const int* __restrict__ dst, int E, int* __restrict__ cnt) {
    int e = blockIdx.x * blockDim.x + threadIdx.x;
    if (e < E) atomicAdd(&cnt[dst[e]], 1);
}

__global__ void dinv_kernel(const int* __restrict__ cnt, float* __restrict__ dinv, int N) {
    int i = blockIdx.x * blockDim.x + threadIdx.x;
    if (i < N) {
        // deg includes the self loop -> always >= 1, no inf guard needed
        dinv[i] = rsqrtf((float)(cnt[i] + 1));
    }
}

// single-block exclusive scan over cnt[0..N) -> rowptr, cursor
__global__ void scan_kernel(const int* __restrict__ cnt, int* __restrict__ rowptr,
                            int* __restrict__ cursor, int N, int E) {
    __shared__ int sm[1024];
    int t = threadIdx.x;
    int C = (N + 1023) >> 10;
    int s0 = t * C;
    int s1 = MIN(N, s0 + C);
    int s = 0;
    for (int i = s0; i < s1; ++i) s += cnt[i];
    sm[t] = s;
    __syncthreads();
    for (int off = 1; off < 1024; off <<= 1) {
        int add = (t >= off) ? sm[t - off] : 0;
        __syncthreads();
        sm[t] += add;
        __syncthreads();
    }
    int excl = sm[t] - s;   // exclusive prefix of this thread's chunk
    for (int i = s0; i < s1; ++i) {
        rowptr[i] = excl;
        cursor[i] = excl;
        excl += cnt[i];
    }
    if (t == 0) rowptr[N] = E;
}

__global__ void fill_kernel(const int* __restrict__ src, const int* __restrict__ dst,
                            int E, int* __restrict__ cursor, int* __restrict__ csr_src) {
    int e = blockIdx.x * blockDim.x + threadIdx.x;
    if (e < E) {
        int d = dst[e];
        int pos = atomicAdd(&cursor[d], 1);
        csr_src[pos] = src[e];
    }
}

// ---------------------------------------------------------------------------
// Aggregation: X[node] = relu( dinv[node]^2 * H[node] + sum_in dinv[s]*dinv[node]*H[s] )
// 256 threads = 4 nodes/block, 1 wave per node, float2 per lane (128 ch).
// ---------------------------------------------------------------------------

__global__ void agg_kernel(const float2* __restrict__ H, const float* __restrict__ dinv,
                           const int* __restrict__ rowptr, const int* __restrict__ csr_src,
                           float2* __restrict__ X, int N) {
    int node = blockIdx.x * 4 + (threadIdx.x >> 6);
    int t = threadIdx.x & 63;
    if (node >= N) return;
    float di = dinv[node];
    float2 h = H[(size_t)node * 64 + t];
    float w0 = di * di;
    float2 acc;
    acc.x = h.x * w0;
    acc.y = h.y * w0;
    int beg = rowptr[node];
    int end = rowptr[node + 1];
    for (int j = beg; j < end; ++j) {
        int s = csr_src[j];
        float w = di * dinv[s];
        float2 hs = H[(size_t)s * 64 + t];
        acc.x = fmaf(hs.x, w, acc.x);
        acc.y = fmaf(hs.y, w, acc.y);
    }
    acc.x = fmaxf(acc.x, 0.0f);
    acc.y = fmaxf(acc.y, 0.0f);
    X[(size_t)node * 64 + t] = acc;
}

// ---------------------------------------------------------------------------
// Tiled fp32 GEMM:  C[i,j] = sum_k A[i*lda+k] * W[j*ldw+k]  (+bias[j]) (+=C) (relu)
// ---------------------------------------------------------------------------

template <int BM, int BN, int BK, int TM, int TN, bool RELU, bool ACCUM, bool BIAS>
__global__ __launch_bounds__((BM / TM) * (BN / TN))
void gemm_kernel(const float* __restrict__ A, int lda,
                 const float* __restrict__ W, int ldw,
                 const float* __restrict__ bias,
                 float* __restrict__ C, int ldc,
                 int M, int K) {
    constexpr int THREADS = (BM / TM) * (BN / TN);
    __shared__ float As[BK][BM + 4];
    __shared__ float Ws[BK][BN + 4];

    int tid = threadIdx.x;
    int tcol = tid % (BN / TN);
    int trow = tid / (BN / TN);
    int rowBase = blockIdx.x * BM;
    int colBase = blockIdx.y * BN;

    float acc[TM][TN];
#pragma unroll
    for (int i = 0; i < TM; ++i)
#pragma unroll
        for (int j = 0; j < TN; ++j) acc[i][j] = 0.0f;

    for (int k0 = 0; k0 < K; k0 += BK) {
        // stage A tile (transposed into As[k][m])
        constexpr int A_F4 = BM * BK / 4;
#pragma unroll
        for (int i = tid; i < A_F4; i += THREADS) {
            int m = i / (BK / 4);
            int kq = (i % (BK / 4)) * 4;
            int gr = rowBase + m;
            float4 v = make_float4(0.f, 0.f, 0.f, 0.f);
            if (gr < M) v = *(const float4*)(A + (size_t)gr * lda + k0 + kq);
            As[kq + 0][m] = v.x;
            As[kq + 1][m] = v.y;
            As[kq + 2][m] = v.z;
            As[kq + 3][m] = v.w;
        }
        // stage W tile (transposed into Ws[k][n])
        constexpr int W_F4 = BN * BK / 4;
#pragma unroll
        for (int i = tid; i < W_F4; i += THREADS) {
            int n = i / (BK / 4);
            int kq = (i % (BK / 4)) * 4;
            float4 v = *(const float4*)(W + (size_t)(colBase + n) * ldw + k0 + kq);
            Ws[kq + 0][n] = v.x;
            Ws[kq + 1][n] = v.y;
            Ws[kq + 2][n] = v.z;
            Ws[kq + 3][n] = v.w;
        }
        __syncthreads();

#pragma unroll
        for (int kk = 0; kk < BK; ++kk) {
            float a[TM], w[TN];
#pragma unroll
            for (int i = 0; i < TM; ++i) a[i] = As[kk][trow * TM + i];
#pragma unroll
            for (int j = 0; j < TN; ++j) w[j] = Ws[kk][tcol * TN + j];
#pragma unroll
            for (int i = 0; i < TM; ++i)
#pragma unroll
                for (int j = 0; j < TN; ++j) acc[i][j] = fmaf(a[i], w[j], acc[i][j]);
        }
        __syncthreads();
    }

    // epilogue
#pragma unroll
    for (int i = 0; i < TM; ++i) {
        int r = rowBase + trow * TM + i;
        if (r < M) {
#pragma unroll
            for (int j = 0; j < TN; ++j) {
                int c = colBase + tcol * TN + j;
                float v = acc[i][j];
                if (BIAS) v += bias[c];
                if (RELU) v = fmaxf(v, 0.0f);
                if (ACCUM) v += C[(size_t)r * ldc + c];
                C[(size_t)r * ldc + c] = v;
            }
        }
    }
}

// ---------------------------------------------------------------------------
// launch
// ---------------------------------------------------------------------------

extern "C" void kernel_launch(void* const* d_in, const int* in_sizes, int n_in,
                              void* d_out, int out_size, void* d_ws, size_t ws_size,
                              hipStream_t stream) {
    const float* x     = (const float*)d_in[0];
    const int*   ei    = (const int*)d_in[1];
    const float* W_in  = (const float*)d_in[2];
    const float* b_in  = (const float*)d_in[3];
    const float* Wc    = (const float*)d_in[4];
    const float* bc    = (const float*)d_in[5];
    const float* W_out = (const float*)d_in[6];
    const float* b_out = (const float*)d_in[7];
    float* out = (float*)d_out;

    const int HID = 128;
    const int N = in_sizes[0] / HID;   // 50000
    const int E = in_sizes[1] / 2;     // 800000
    const int L = 4;
    const int* src = ei;
    const int* dst = ei + E;

    // workspace carve-up (256B aligned)
    char* ws = (char*)d_ws;
    size_t off = 0;
    auto carve = [&](size_t bytes) {
        void* p = ws + off;
        off += (bytes + 255) & ~(size_t)255;
        return p;
    };
    float* dinv    = (float*)carve((size_t)N * 4);
    int*   cnt     = (int*)carve((size_t)N * 4);
    int*   rowptr  = (int*)carve((size_t)(N + 1) * 4);
    int*   cursor  = (int*)carve((size_t)N * 4);
    int*   csr_src = (int*)carve((size_t)E * 4);
    float* bufA    = (float*)carve((size_t)N * HID * 4);  // layer activations
    float* bufH    = (float*)carve((size_t)N * HID * 4);  // pre-aggregation GEMM out
    (void)ws_size;

    // ---- CSR + norm build ----
    hipMemsetAsync(cnt, 0, (size_t)N * 4, stream);
    count_kernel<<<(E + 255) / 256, 256, 0, stream>>>(dst, E, cnt);
    dinv_kernel<<<(N + 255) / 256, 256, 0, stream>>>(cnt, dinv, N);
    scan_kernel<<<1, 1024, 0, stream>>>(cnt, rowptr, cursor, N, E);
    fill_kernel<<<(E + 255) / 256, 256, 0, stream>>>(src, dst, E, cursor, csr_src);

    dim3 gemm_grid((N + 127) / 128, 1);

    // ---- input projection: bufA = relu(x @ W_in^T + b_in) ----
    gemm_kernel<128, 128, 16, 8, 8, true, false, true>
        <<<gemm_grid, 256, 0, stream>>>(x, HID, W_in, HID, b_in, bufA, HID, N, HID);

    // ---- conv layers ----
    for (int l = 0; l < L; ++l) {
        // bufH = bufA @ Wc[l]^T + bc[l]
        gemm_kernel<128, 128, 16, 8, 8, false, false, true>
            <<<gemm_grid, 256, 0, stream>>>(bufA, HID, Wc + (size_t)l * HID * HID, HID,
                                            bc + (size_t)l * HID, bufH, HID, N, HID);
        // bufA = relu(aggregate(bufH))
        agg_kernel<<<(N + 3) / 4, 256, 0, stream>>>((const float2*)bufH, dinv, rowptr,
                                                    csr_src, (float2*)bufA, N);
        // out (+)= bufA @ W_out[:, l*128:(l+1)*128]^T  (+ b_out at l==0)
        if (l == 0) {
            gemm_kernel<128, 64, 32, 8, 4, false, false, true>
                <<<gemm_grid, 256, 0, stream>>>(bufA, HID, W_out + (size_t)l * HID, 512,
                                                b_out, out, 64, N, HID);
        } else {
            gemm_kernel<128, 64, 32, 8, 4, false, true, false>
                <<<gemm_grid, 256, 0, stream>>>(bufA, HID, W_out + (size_t)l * HID, 512,
                                                nullptr, out, 64, N, HID);
        }
    }
}

// Round 2
// 770.573 us; speedup vs baseline: 1.1228x; 1.1228x over previous
//
#include <hip/hip_runtime.h>

#ifndef MIN
#define MIN(a,b) ((a)<(b)?(a):(b))
#endif

// ---------------------------------------------------------------------------
// CSR build kernels
// ---------------------------------------------------------------------------

__global__ void count_kernel(const int* __restrict__ dst, int E, int* __restrict__ cnt) {
    int e = blockIdx.x * blockDim.x + threadIdx.x;
    if (e < E) atomicAdd(&cnt[dst[e]], 1);
}

__global__ void dinv_kernel(const int* __restrict__ cnt, float* __restrict__ dinv, int N) {
    int i = blockIdx.x * blockDim.x + threadIdx.x;
    if (i < N) {
        // deg includes the self loop -> always >= 1, no inf guard needed
        dinv[i] = rsqrtf((float)(cnt[i] + 1));
    }
}

// ---- multi-block exclusive scan over cnt[0..N) -> rowptr, cursor ----
// Phase 1: each 256-thread block sums a 1024-element chunk -> blockSums[b]
__global__ void scan_phase1(const int* __restrict__ cnt, int N, int* __restrict__ blockSums) {
    int b = blockIdx.x;
    int t = threadIdx.x;
    int base = b * 1024 + t * 4;
    int s = 0;
#pragma unroll
    for (int k = 0; k < 4; ++k) {
        int i = base + k;
        if (i < N) s += cnt[i];
    }
    __shared__ int sm[256];
    sm[t] = s;
    __syncthreads();
    for (int off = 128; off > 0; off >>= 1) {
        if (t < off) sm[t] += sm[t + off];
        __syncthreads();
    }
    if (t == 0) blockSums[b] = sm[0];
}

// Phase 2: one block scans B (<=1024) block sums -> exclusive blockOffsets
__global__ void scan_phase2(const int* __restrict__ blockSums, int* __restrict__ blockOffsets, int B) {
    __shared__ int sm[1024];
    int t = threadIdx.x;
    int v = (t < B) ? blockSums[t] : 0;
    sm[t] = v;
    __syncthreads();
    for (int off = 1; off < 1024; off <<= 1) {
        int add = (t >= off) ? sm[t - off] : 0;
        __syncthreads();
        sm[t] += add;
        __syncthreads();
    }
    if (t < B) blockOffsets[t] = sm[t] - v;   // exclusive
}

// Phase 3: per-block local exclusive scan + global offset -> rowptr, cursor
__global__ void scan_phase3(const int* __restrict__ cnt, const int* __restrict__ blockOffsets,
                            int* __restrict__ rowptr, int* __restrict__ cursor, int N, int E) {
    int b = blockIdx.x;
    int t = threadIdx.x;
    int base = b * 1024 + t * 4;
    int v[4];
    int s = 0;
#pragma unroll
    for (int k = 0; k < 4; ++k) {
        int i = base + k;
        v[k] = (i < N) ? cnt[i] : 0;
        s += v[k];
    }
    __shared__ int sm[256];
    sm[t] = s;
    __syncthreads();
    for (int off = 1; off < 256; off <<= 1) {
        int add = (t >= off) ? sm[t - off] : 0;
        __syncthreads();
        sm[t] += add;
        __syncthreads();
    }
    int excl = sm[t] - s + blockOffsets[b];
#pragma unroll
    for (int k = 0; k < 4; ++k) {
        int i = base + k;
        if (i < N) {
            rowptr[i] = excl;
            cursor[i] = excl;
            excl += v[k];
        }
    }
    if (b == 0 && t == 0) rowptr[N] = E;
}

__global__ void fill_kernel(const int* __restrict__ src, const int* __restrict__ dst,
                            int E, int* __restrict__ cursor, int* __restrict__ csr_src) {
    int e = blockIdx.x * blockDim.x + threadIdx.x;
    if (e < E) {
        int d = dst[e];
        int pos = atomicAdd(&cursor[d], 1);
        csr_src[pos] = src[e];
    }
}

// ---------------------------------------------------------------------------
// Aggregation: X[node] = relu( dinv[node]^2 * H[node] + sum_in dinv[s]*dinv[node]*H[s] )
// 256 threads = 4 nodes/block, 1 wave per node, float2 per lane (128 ch).
// ---------------------------------------------------------------------------

__global__ void agg_kernel(const float2* __restrict__ H, const float* __restrict__ dinv,
                           const int* __restrict__ rowptr, const int* __restrict__ csr_src,
                           float2* __restrict__ X, int N) {
    int node = blockIdx.x * 4 + (threadIdx.x >> 6);
    int t = threadIdx.x & 63;
    if (node >= N) return;
    float di = dinv[node];
    float2 h = H[(size_t)node * 64 + t];
    float w0 = di * di;
    float2 acc;
    acc.x = h.x * w0;
    acc.y = h.y * w0;
    int beg = rowptr[node];
    int end = rowptr[node + 1];
    for (int j = beg; j < end; ++j) {
        int s = csr_src[j];
        float w = di * dinv[s];
        float2 hs = H[(size_t)s * 64 + t];
        acc.x = fmaf(hs.x, w, acc.x);
        acc.y = fmaf(hs.y, w, acc.y);
    }
    acc.x = fmaxf(acc.x, 0.0f);
    acc.y = fmaxf(acc.y, 0.0f);
    X[(size_t)node * 64 + t] = acc;
}

// ---------------------------------------------------------------------------
// Tiled fp32 GEMM:  C[i,j] = sum_k A[i*lda+k] * W[j*ldw+k]  (+bias[j]) (+=C) (relu)
// ---------------------------------------------------------------------------

template <int BM, int BN, int BK, int TM, int TN, bool RELU, bool ACCUM, bool BIAS>
__global__ __launch_bounds__((BM / TM) * (BN / TN))
void gemm_kernel(const float* __restrict__ A, int lda,
                 const float* __restrict__ W, int ldw,
                 const float* __restrict__ bias,
                 float* __restrict__ C, int ldc,
                 int M, int K) {
    constexpr int THREADS = (BM / TM) * (BN / TN);
    __shared__ float As[BK][BM + 4];
    __shared__ float Ws[BK][BN + 4];

    int tid = threadIdx.x;
    int tcol = tid % (BN / TN);
    int trow = tid / (BN / TN);
    int rowBase = blockIdx.x * BM;
    int colBase = blockIdx.y * BN;

    float acc[TM][TN];
#pragma unroll
    for (int i = 0; i < TM; ++i)
#pragma unroll
        for (int j = 0; j < TN; ++j) acc[i][j] = 0.0f;

    for (int k0 = 0; k0 < K; k0 += BK) {
        // stage A tile (transposed into As[k][m])
        constexpr int A_F4 = BM * BK / 4;
#pragma unroll
        for (int i = tid; i < A_F4; i += THREADS) {
            int m = i / (BK / 4);
            int kq = (i % (BK / 4)) * 4;
            int gr = rowBase + m;
            float4 v = make_float4(0.f, 0.f, 0.f, 0.f);
            if (gr < M) v = *(const float4*)(A + (size_t)gr * lda + k0 + kq);
            As[kq + 0][m] = v.x;
            As[kq + 1][m] = v.y;
            As[kq + 2][m] = v.z;
            As[kq + 3][m] = v.w;
        }
        // stage W tile (transposed into Ws[k][n])
        constexpr int W_F4 = BN * BK / 4;
#pragma unroll
        for (int i = tid; i < W_F4; i += THREADS) {
            int n = i / (BK / 4);
            int kq = (i % (BK / 4)) * 4;
            float4 v = *(const float4*)(W + (size_t)(colBase + n) * ldw + k0 + kq);
            Ws[kq + 0][n] = v.x;
            Ws[kq + 1][n] = v.y;
            Ws[kq + 2][n] = v.z;
            Ws[kq + 3][n] = v.w;
        }
        __syncthreads();

#pragma unroll
        for (int kk = 0; kk < BK; ++kk) {
            float a[TM], w[TN];
#pragma unroll
            for (int i = 0; i < TM; ++i) a[i] = As[kk][trow * TM + i];
#pragma unroll
            for (int j = 0; j < TN; ++j) w[j] = Ws[kk][tcol * TN + j];
#pragma unroll
            for (int i = 0; i < TM; ++i)
#pragma unroll
                for (int j = 0; j < TN; ++j) acc[i][j] = fmaf(a[i], w[j], acc[i][j]);
        }
        __syncthreads();
    }

    // epilogue
#pragma unroll
    for (int i = 0; i < TM; ++i) {
        int r = rowBase + trow * TM + i;
        if (r < M) {
#pragma unroll
            for (int j = 0; j < TN; ++j) {
                int c = colBase + tcol * TN + j;
                float v = acc[i][j];
                if (BIAS) v += bias[c];
                if (RELU) v = fmaxf(v, 0.0f);
                if (ACCUM) v += C[(size_t)r * ldc + c];
                C[(size_t)r * ldc + c] = v;
            }
        }
    }
}

// ---------------------------------------------------------------------------
// launch
// ---------------------------------------------------------------------------

extern "C" void kernel_launch(void* const* d_in, const int* in_sizes, int n_in,
                              void* d_out, int out_size, void* d_ws, size_t ws_size,
                              hipStream_t stream) {
    const float* x     = (const float*)d_in[0];
    const int*   ei    = (const int*)d_in[1];
    const float* W_in  = (const float*)d_in[2];
    const float* b_in  = (const float*)d_in[3];
    const float* Wc    = (const float*)d_in[4];
    const float* bc    = (const float*)d_in[5];
    const float* W_out = (const float*)d_in[6];
    const float* b_out = (const float*)d_in[7];
    float* out = (float*)d_out;

    const int HID = 128;
    const int N = in_sizes[0] / HID;   // 50000
    const int E = in_sizes[1] / 2;     // 800000
    const int L = 4;
    const int* src = ei;
    const int* dst = ei + E;

    // workspace carve-up (256B aligned)
    char* ws = (char*)d_ws;
    size_t off = 0;
    auto carve = [&](size_t bytes) {
        void* p = ws + off;
        off += (bytes + 255) & ~(size_t)255;
        return p;
    };
    float* dinv      = (float*)carve((size_t)N * 4);
    int*   cnt       = (int*)carve((size_t)N * 4);
    int*   rowptr    = (int*)carve((size_t)(N + 1) * 4);
    int*   cursor    = (int*)carve((size_t)N * 4);
    int*   csr_src   = (int*)carve((size_t)E * 4);
    float* bufA      = (float*)carve((size_t)N * HID * 4);  // layer activations
    float* bufH      = (float*)carve((size_t)N * HID * 4);  // pre-aggregation GEMM out
    int*   blockSums = (int*)carve((size_t)1024 * 4);
    int*   blockOffs = (int*)carve((size_t)1024 * 4);
    (void)ws_size;

    // ---- CSR + norm build ----
    hipMemsetAsync(cnt, 0, (size_t)N * 4, stream);
    count_kernel<<<(E + 255) / 256, 256, 0, stream>>>(dst, E, cnt);
    dinv_kernel<<<(N + 255) / 256, 256, 0, stream>>>(cnt, dinv, N);
    int B = (N + 1023) / 1024;   // 49 for N=50000
    scan_phase1<<<B, 256, 0, stream>>>(cnt, N, blockSums);
    scan_phase2<<<1, 1024, 0, stream>>>(blockSums, blockOffs, B);
    scan_phase3<<<B, 256, 0, stream>>>(cnt, blockOffs, rowptr, cursor, N, E);
    fill_kernel<<<(E + 255) / 256, 256, 0, stream>>>(src, dst, E, cursor, csr_src);

    dim3 gemm_grid((N + 127) / 128, 1);

    // ---- input projection: bufA = relu(x @ W_in^T + b_in) ----
    gemm_kernel<128, 128, 16, 8, 8, true, false, true>
        <<<gemm_grid, 256, 0, stream>>>(x, HID, W_in, HID, b_in, bufA, HID, N, HID);

    // ---- conv layers ----
    for (int l = 0; l < L; ++l) {
        // bufH = bufA @ Wc[l]^T + bc[l]
        gemm_kernel<128, 128, 16, 8, 8, false, false, true>
            <<<gemm_grid, 256, 0, stream>>>(bufA, HID, Wc + (size_t)l * HID * HID, HID,
                                            bc + (size_t)l * HID, bufH, HID, N, HID);
        // bufA = relu(aggregate(bufH))
        agg_kernel<<<(N + 3) / 4, 256, 0, stream>>>((const float2*)bufH, dinv, rowptr,
                                                    csr_src, (float2*)bufA, N);
        // out (+)= bufA @ W_out[:, l*128:(l+1)*128]^T  (+ b_out at l==0)
        if (l == 0) {
            gemm_kernel<128, 64, 32, 8, 4, false, false, true>
                <<<gemm_grid, 256, 0, stream>>>(bufA, HID, W_out + (size_t)l * HID, 512,
                                                b_out, out, 64, N, HID);
        } else {
            gemm_kernel<128, 64, 32, 8, 4, false, true, false>
                <<<gemm_grid, 256, 0, stream>>>(bufA, HID, W_out + (size_t)l * HID, 512,
                                                nullptr, out, 64, N, HID);
        }
    }
}

// Round 3
// 659.082 us; speedup vs baseline: 1.3128x; 1.1692x over previous
//
#include <hip/hip_runtime.h>

#ifndef MIN
#define MIN(a,b) ((a)<(b)?(a):(b))
#endif

// ---------------------------------------------------------------------------
// CSR build kernels
// ---------------------------------------------------------------------------

__global__ void count_kernel(const int* __restrict__ dst, int E, int* __restrict__ cnt) {
    int e = blockIdx.x * blockDim.x + threadIdx.x;
    if (e < E) atomicAdd(&cnt[dst[e]], 1);
}

__global__ void dinv_kernel(const int* __restrict__ cnt, float* __restrict__ dinv, int N) {
    int i = blockIdx.x * blockDim.x + threadIdx.x;
    if (i < N) {
        // deg includes the self loop -> always >= 1, no inf guard needed
        dinv[i] = rsqrtf((float)(cnt[i] + 1));
    }
}

// ---- multi-block exclusive scan over cnt[0..N) -> rowptr, cursor ----
__global__ void scan_phase1(const int* __restrict__ cnt, int N, int* __restrict__ blockSums) {
    int b = blockIdx.x;
    int t = threadIdx.x;
    int base = b * 1024 + t * 4;
    int s = 0;
#pragma unroll
    for (int k = 0; k < 4; ++k) {
        int i = base + k;
        if (i < N) s += cnt[i];
    }
    __shared__ int sm[256];
    sm[t] = s;
    __syncthreads();
    for (int off = 128; off > 0; off >>= 1) {
        if (t < off) sm[t] += sm[t + off];
        __syncthreads();
    }
    if (t == 0) blockSums[b] = sm[0];
}

__global__ void scan_phase2(const int* __restrict__ blockSums, int* __restrict__ blockOffsets, int B) {
    __shared__ int sm[1024];
    int t = threadIdx.x;
    int v = (t < B) ? blockSums[t] : 0;
    sm[t] = v;
    __syncthreads();
    for (int off = 1; off < 1024; off <<= 1) {
        int add = (t >= off) ? sm[t - off] : 0;
        __syncthreads();
        sm[t] += add;
        __syncthreads();
    }
    if (t < B) blockOffsets[t] = sm[t] - v;   // exclusive
}

__global__ void scan_phase3(const int* __restrict__ cnt, const int* __restrict__ blockOffsets,
                            int* __restrict__ rowptr, int* __restrict__ cursor, int N, int E) {
    int b = blockIdx.x;
    int t = threadIdx.x;
    int base = b * 1024 + t * 4;
    int v[4];
    int s = 0;
#pragma unroll
    for (int k = 0; k < 4; ++k) {
        int i = base + k;
        v[k] = (i < N) ? cnt[i] : 0;
        s += v[k];
    }
    __shared__ int sm[256];
    sm[t] = s;
    __syncthreads();
    for (int off = 1; off < 256; off <<= 1) {
        int add = (t >= off) ? sm[t - off] : 0;
        __syncthreads();
        sm[t] += add;
        __syncthreads();
    }
    int excl = sm[t] - s + blockOffsets[b];
#pragma unroll
    for (int k = 0; k < 4; ++k) {
        int i = base + k;
        if (i < N) {
            rowptr[i] = excl;
            cursor[i] = excl;
            excl += v[k];
        }
    }
    if (b == 0 && t == 0) rowptr[N] = E;
}

__global__ void fill_kernel(const int* __restrict__ src, const int* __restrict__ dst,
                            int E, int* __restrict__ cursor, int* __restrict__ csr_src) {
    int e = blockIdx.x * blockDim.x + threadIdx.x;
    if (e < E) {
        int d = dst[e];
        int pos = atomicAdd(&cursor[d], 1);
        csr_src[pos] = src[e];
    }
}

// ---------------------------------------------------------------------------
// Aggregation: X[node] = relu( di * ( di*H[node] + sum_in dinv[s]*H[s] ) )
// 1 wave per node. Batch 64 edges per wave (one csr_src/dinv gather),
// broadcast via shfl, 8 independent H-row gathers in flight.
// ---------------------------------------------------------------------------

__global__ void agg_kernel(const float2* __restrict__ H, const float* __restrict__ dinv,
                           const int* __restrict__ rowptr, const int* __restrict__ csr_src,
                           float2* __restrict__ X, int N) {
    int node = blockIdx.x * 4 + (threadIdx.x >> 6);
    int t = threadIdx.x & 63;
    if (node >= N) return;
    float di = dinv[node];
    float2 h = H[(size_t)node * 64 + t];
    float2 acc;
    acc.x = h.x * di;
    acc.y = h.y * di;
    int beg = rowptr[node];
    int end = rowptr[node + 1];

    for (int base = beg; base < end; base += 64) {
        int idx = base + t;
        bool valid = idx < end;
        int s_lane = valid ? csr_src[idx] : node;    // safe address for pads
        float w_lane = valid ? dinv[s_lane] : 0.0f;  // zero weight for pads
        int m = end - base;
        if (m > 64) m = 64;
        int mm = (m + 7) & ~7;                       // pads contribute 0
        for (int j = 0; j < mm; j += 8) {
            int s0 = __shfl(s_lane, j + 0), s1 = __shfl(s_lane, j + 1);
            int s2 = __shfl(s_lane, j + 2), s3 = __shfl(s_lane, j + 3);
            int s4 = __shfl(s_lane, j + 4), s5 = __shfl(s_lane, j + 5);
            int s6 = __shfl(s_lane, j + 6), s7 = __shfl(s_lane, j + 7);
            float w0 = __shfl(w_lane, j + 0), w1 = __shfl(w_lane, j + 1);
            float w2 = __shfl(w_lane, j + 2), w3 = __shfl(w_lane, j + 3);
            float w4 = __shfl(w_lane, j + 4), w5 = __shfl(w_lane, j + 5);
            float w6 = __shfl(w_lane, j + 6), w7 = __shfl(w_lane, j + 7);
            float2 h0 = H[(size_t)s0 * 64 + t];
            float2 h1 = H[(size_t)s1 * 64 + t];
            float2 h2 = H[(size_t)s2 * 64 + t];
            float2 h3 = H[(size_t)s3 * 64 + t];
            float2 h4 = H[(size_t)s4 * 64 + t];
            float2 h5 = H[(size_t)s5 * 64 + t];
            float2 h6 = H[(size_t)s6 * 64 + t];
            float2 h7 = H[(size_t)s7 * 64 + t];
            acc.x = fmaf(h0.x, w0, acc.x); acc.y = fmaf(h0.y, w0, acc.y);
            acc.x = fmaf(h1.x, w1, acc.x); acc.y = fmaf(h1.y, w1, acc.y);
            acc.x = fmaf(h2.x, w2, acc.x); acc.y = fmaf(h2.y, w2, acc.y);
            acc.x = fmaf(h3.x, w3, acc.x); acc.y = fmaf(h3.y, w3, acc.y);
            acc.x = fmaf(h4.x, w4, acc.x); acc.y = fmaf(h4.y, w4, acc.y);
            acc.x = fmaf(h5.x, w5, acc.x); acc.y = fmaf(h5.y, w5, acc.y);
            acc.x = fmaf(h6.x, w6, acc.x); acc.y = fmaf(h6.y, w6, acc.y);
            acc.x = fmaf(h7.x, w7, acc.x); acc.y = fmaf(h7.y, w7, acc.y);
        }
    }
    acc.x = fmaxf(acc.x * di, 0.0f);
    acc.y = fmaxf(acc.y * di, 0.0f);
    X[(size_t)node * 64 + t] = acc;
}

// ---------------------------------------------------------------------------
// Tiled fp32 GEMM:  C[i,j] = sum_k A[i*lda+k] * W[j*ldw+k]  (+bias[j]) (+=C) (relu)
// ---------------------------------------------------------------------------

template <int BM, int BN, int BK, int TM, int TN, bool RELU, bool ACCUM, bool BIAS>
__global__ __launch_bounds__((BM / TM) * (BN / TN))
void gemm_kernel(const float* __restrict__ A, int lda,
                 const float* __restrict__ W, int ldw,
                 const float* __restrict__ bias,
                 float* __restrict__ C, int ldc,
                 int M, int K) {
    constexpr int THREADS = (BM / TM) * (BN / TN);
    __shared__ float As[BK][BM + 4];
    __shared__ float Ws[BK][BN + 4];

    int tid = threadIdx.x;
    int tcol = tid % (BN / TN);
    int trow = tid / (BN / TN);
    int rowBase = blockIdx.x * BM;
    int colBase = blockIdx.y * BN;

    float acc[TM][TN];
#pragma unroll
    for (int i = 0; i < TM; ++i)
#pragma unroll
        for (int j = 0; j < TN; ++j) acc[i][j] = 0.0f;

    for (int k0 = 0; k0 < K; k0 += BK) {
        constexpr int A_F4 = BM * BK / 4;
#pragma unroll
        for (int i = tid; i < A_F4; i += THREADS) {
            int m = i / (BK / 4);
            int kq = (i % (BK / 4)) * 4;
            int gr = rowBase + m;
            float4 v = make_float4(0.f, 0.f, 0.f, 0.f);
            if (gr < M) v = *(const float4*)(A + (size_t)gr * lda + k0 + kq);
            As[kq + 0][m] = v.x;
            As[kq + 1][m] = v.y;
            As[kq + 2][m] = v.z;
            As[kq + 3][m] = v.w;
        }
        constexpr int W_F4 = BN * BK / 4;
#pragma unroll
        for (int i = tid; i < W_F4; i += THREADS) {
            int n = i / (BK / 4);
            int kq = (i % (BK / 4)) * 4;
            float4 v = *(const float4*)(W + (size_t)(colBase + n) * ldw + k0 + kq);
            Ws[kq + 0][n] = v.x;
            Ws[kq + 1][n] = v.y;
            Ws[kq + 2][n] = v.z;
            Ws[kq + 3][n] = v.w;
        }
        __syncthreads();

#pragma unroll
        for (int kk = 0; kk < BK; ++kk) {
            float a[TM], w[TN];
#pragma unroll
            for (int i = 0; i < TM; ++i) a[i] = As[kk][trow * TM + i];
#pragma unroll
            for (int j = 0; j < TN; ++j) w[j] = Ws[kk][tcol * TN + j];
#pragma unroll
            for (int i = 0; i < TM; ++i)
#pragma unroll
                for (int j = 0; j < TN; ++j) acc[i][j] = fmaf(a[i], w[j], acc[i][j]);
        }
        __syncthreads();
    }

#pragma unroll
    for (int i = 0; i < TM; ++i) {
        int r = rowBase + trow * TM + i;
        if (r < M) {
#pragma unroll
            for (int j = 0; j < TN; ++j) {
                int c = colBase + tcol * TN + j;
                float v = acc[i][j];
                if (BIAS) v += bias[c];
                if (RELU) v = fmaxf(v, 0.0f);
                if (ACCUM) v += C[(size_t)r * ldc + c];
                C[(size_t)r * ldc + c] = v;
            }
        }
    }
}

// ---------------------------------------------------------------------------
// launch
// ---------------------------------------------------------------------------

extern "C" void kernel_launch(void* const* d_in, const int* in_sizes, int n_in,
                              void* d_out, int out_size, void* d_ws, size_t ws_size,
                              hipStream_t stream) {
    const float* x     = (const float*)d_in[0];
    const int*   ei    = (const int*)d_in[1];
    const float* W_in  = (const float*)d_in[2];
    const float* b_in  = (const float*)d_in[3];
    const float* Wc    = (const float*)d_in[4];
    const float* bc    = (const float*)d_in[5];
    const float* W_out = (const float*)d_in[6];
    const float* b_out = (const float*)d_in[7];
    float* out = (float*)d_out;

    const int HID = 128;
    const int N = in_sizes[0] / HID;   // 50000
    const int E = in_sizes[1] / 2;     // 800000
    const int L = 4;
    const int* src = ei;
    const int* dst = ei + E;

    char* ws = (char*)d_ws;
    size_t off = 0;
    auto carve = [&](size_t bytes) {
        void* p = ws + off;
        off += (bytes + 255) & ~(size_t)255;
        return p;
    };
    float* dinv      = (float*)carve((size_t)N * 4);
    int*   cnt       = (int*)carve((size_t)N * 4);
    int*   rowptr    = (int*)carve((size_t)(N + 1) * 4);
    int*   cursor    = (int*)carve((size_t)N * 4);
    int*   csr_src   = (int*)carve((size_t)E * 4);
    float* bufA      = (float*)carve((size_t)N * HID * 4);
    float* bufH      = (float*)carve((size_t)N * HID * 4);
    int*   blockSums = (int*)carve((size_t)1024 * 4);
    int*   blockOffs = (int*)carve((size_t)1024 * 4);
    (void)ws_size;

    // ---- CSR + norm build ----
    hipMemsetAsync(cnt, 0, (size_t)N * 4, stream);
    count_kernel<<<(E + 255) / 256, 256, 0, stream>>>(dst, E, cnt);
    dinv_kernel<<<(N + 255) / 256, 256, 0, stream>>>(cnt, dinv, N);
    int B = (N + 1023) / 1024;
    scan_phase1<<<B, 256, 0, stream>>>(cnt, N, blockSums);
    scan_phase2<<<1, 1024, 0, stream>>>(blockSums, blockOffs, B);
    scan_phase3<<<B, 256, 0, stream>>>(cnt, blockOffs, rowptr, cursor, N, E);
    fill_kernel<<<(E + 255) / 256, 256, 0, stream>>>(src, dst, E, cursor, csr_src);

    dim3 gemm_grid((N + 127) / 128, 1);

    // ---- input projection: bufA = relu(x @ W_in^T + b_in) ----
    gemm_kernel<128, 128, 16, 8, 8, true, false, true>
        <<<gemm_grid, 256, 0, stream>>>(x, HID, W_in, HID, b_in, bufA, HID, N, HID);

    // ---- conv layers ----
    for (int l = 0; l < L; ++l) {
        gemm_kernel<128, 128, 16, 8, 8, false, false, true>
            <<<gemm_grid, 256, 0, stream>>>(bufA, HID, Wc + (size_t)l * HID * HID, HID,
                                            bc + (size_t)l * HID, bufH, HID, N, HID);
        agg_kernel<<<(N + 3) / 4, 256, 0, stream>>>((const float2*)bufH, dinv, rowptr,
                                                    csr_src, (float2*)bufA, N);
        if (l == 0) {
            gemm_kernel<128, 64, 32, 8, 4, false, false, true>
                <<<gemm_grid, 256, 0, stream>>>(bufA, HID, W_out + (size_t)l * HID, 512,
                                                b_out, out, 64, N, HID);
        } else {
            gemm_kernel<128, 64, 32, 8, 4, false, true, false>
                <<<gemm_grid, 256, 0, stream>>>(bufA, HID, W_out + (size_t)l * HID, 512,
                                                nullptr, out, 64, N, HID);
        }
    }
}

// Round 4
// 536.384 us; speedup vs baseline: 1.6131x; 1.2288x over previous
//
#include <hip/hip_runtime.h>
#include <hip/hip_bf16.h>

#ifndef MIN
#define MIN(a,b) ((a)<(b)?(a):(b))
#endif

// ---------------------------------------------------------------------------
// CSR build kernels
// ---------------------------------------------------------------------------

__global__ void count_kernel(const int* __restrict__ dst, int E, int* __restrict__ cnt) {
    int e = blockIdx.x * blockDim.x + threadIdx.x;
    if (e < E) atomicAdd(&cnt[dst[e]], 1);
}

__global__ void dinv_kernel(const int* __restrict__ cnt, float* __restrict__ dinv, int N) {
    int i = blockIdx.x * blockDim.x + threadIdx.x;
    if (i < N) {
        dinv[i] = rsqrtf((float)(cnt[i] + 1));   // self loop -> deg >= 1
    }
}

// ---- multi-block exclusive scan over cnt[0..N) -> rowptr, cursor ----
__global__ void scan_phase1(const int* __restrict__ cnt, int N, int* __restrict__ blockSums) {
    int b = blockIdx.x;
    int t = threadIdx.x;
    int base = b * 1024 + t * 4;
    int s = 0;
#pragma unroll
    for (int k = 0; k < 4; ++k) {
        int i = base + k;
        if (i < N) s += cnt[i];
    }
    __shared__ int sm[256];
    sm[t] = s;
    __syncthreads();
    for (int off = 128; off > 0; off >>= 1) {
        if (t < off) sm[t] += sm[t + off];
        __syncthreads();
    }
    if (t == 0) blockSums[b] = sm[0];
}

__global__ void scan_phase2(const int* __restrict__ blockSums, int* __restrict__ blockOffsets, int B) {
    __shared__ int sm[1024];
    int t = threadIdx.x;
    int v = (t < B) ? blockSums[t] : 0;
    sm[t] = v;
    __syncthreads();
    for (int off = 1; off < 1024; off <<= 1) {
        int add = (t >= off) ? sm[t - off] : 0;
        __syncthreads();
        sm[t] += add;
        __syncthreads();
    }
    if (t < B) blockOffsets[t] = sm[t] - v;   // exclusive
}

__global__ void scan_phase3(const int* __restrict__ cnt, const int* __restrict__ blockOffsets,
                            int* __restrict__ rowptr, int* __restrict__ cursor, int N, int E) {
    int b = blockIdx.x;
    int t = threadIdx.x;
    int base = b * 1024 + t * 4;
    int v[4];
    int s = 0;
#pragma unroll
    for (int k = 0; k < 4; ++k) {
        int i = base + k;
        v[k] = (i < N) ? cnt[i] : 0;
        s += v[k];
    }
    __shared__ int sm[256];
    sm[t] = s;
    __syncthreads();
    for (int off = 1; off < 256; off <<= 1) {
        int add = (t >= off) ? sm[t - off] : 0;
        __syncthreads();
        sm[t] += add;
        __syncthreads();
    }
    int excl = sm[t] - s + blockOffsets[b];
#pragma unroll
    for (int k = 0; k < 4; ++k) {
        int i = base + k;
        if (i < N) {
            rowptr[i] = excl;
            cursor[i] = excl;
            excl += v[k];
        }
    }
    if (b == 0 && t == 0) rowptr[N] = E;
}

__global__ void fill_kernel(const int* __restrict__ src, const int* __restrict__ dst,
                            int E, int* __restrict__ cursor, int* __restrict__ csr_src) {
    int e = blockIdx.x * blockDim.x + threadIdx.x;
    if (e < E) {
        int d = dst[e];
        int pos = atomicAdd(&cursor[d], 1);
        csr_src[pos] = src[e];
    }
}

// ---------------------------------------------------------------------------
// Aggregation over bf16 H: X[node] = relu( di*( di*H[node] + sum dinv[s]*H[s] ) )
// 1 wave per node, 1 dword (2 bf16 ch) per lane; 64-edge batches via shfl,
// 8 independent row gathers in flight. Accumulate fp32; X written fp32.
// ---------------------------------------------------------------------------

__device__ __forceinline__ float bf16_hi(unsigned u) {
    return __uint_as_float(u << 16);
}

__global__ void agg_kernel(const ushort2* __restrict__ Hb, const float* __restrict__ dinv,
                           const int* __restrict__ rowptr, const int* __restrict__ csr_src,
                           float2* __restrict__ X, int N) {
    int node = blockIdx.x * 4 + (threadIdx.x >> 6);
    int t = threadIdx.x & 63;
    if (node >= N) return;
    float di = dinv[node];
    ushort2 hu = Hb[(size_t)node * 64 + t];
    float2 acc;
    acc.x = bf16_hi(hu.x) * di;
    acc.y = bf16_hi(hu.y) * di;
    int beg = rowptr[node];
    int end = rowptr[node + 1];

    for (int base = beg; base < end; base += 64) {
        int idx = base + t;
        bool valid = idx < end;
        int s_lane = valid ? csr_src[idx] : node;    // safe address for pads
        float w_lane = valid ? dinv[s_lane] : 0.0f;  // zero weight for pads
        int m = end - base;
        if (m > 64) m = 64;
        int mm = (m + 7) & ~7;                       // pads contribute 0
        for (int j = 0; j < mm; j += 8) {
            int s0 = __shfl(s_lane, j + 0), s1 = __shfl(s_lane, j + 1);
            int s2 = __shfl(s_lane, j + 2), s3 = __shfl(s_lane, j + 3);
            int s4 = __shfl(s_lane, j + 4), s5 = __shfl(s_lane, j + 5);
            int s6 = __shfl(s_lane, j + 6), s7 = __shfl(s_lane, j + 7);
            float w0 = __shfl(w_lane, j + 0), w1 = __shfl(w_lane, j + 1);
            float w2 = __shfl(w_lane, j + 2), w3 = __shfl(w_lane, j + 3);
            float w4 = __shfl(w_lane, j + 4), w5 = __shfl(w_lane, j + 5);
            float w6 = __shfl(w_lane, j + 6), w7 = __shfl(w_lane, j + 7);
            ushort2 u0 = Hb[(size_t)s0 * 64 + t];
            ushort2 u1 = Hb[(size_t)s1 * 64 + t];
            ushort2 u2 = Hb[(size_t)s2 * 64 + t];
            ushort2 u3 = Hb[(size_t)s3 * 64 + t];
            ushort2 u4 = Hb[(size_t)s4 * 64 + t];
            ushort2 u5 = Hb[(size_t)s5 * 64 + t];
            ushort2 u6 = Hb[(size_t)s6 * 64 + t];
            ushort2 u7 = Hb[(size_t)s7 * 64 + t];
            acc.x = fmaf(bf16_hi(u0.x), w0, acc.x); acc.y = fmaf(bf16_hi(u0.y), w0, acc.y);
            acc.x = fmaf(bf16_hi(u1.x), w1, acc.x); acc.y = fmaf(bf16_hi(u1.y), w1, acc.y);
            acc.x = fmaf(bf16_hi(u2.x), w2, acc.x); acc.y = fmaf(bf16_hi(u2.y), w2, acc.y);
            acc.x = fmaf(bf16_hi(u3.x), w3, acc.x); acc.y = fmaf(bf16_hi(u3.y), w3, acc.y);
            acc.x = fmaf(bf16_hi(u4.x), w4, acc.x); acc.y = fmaf(bf16_hi(u4.y), w4, acc.y);
            acc.x = fmaf(bf16_hi(u5.x), w5, acc.x); acc.y = fmaf(bf16_hi(u5.y), w5, acc.y);
            acc.x = fmaf(bf16_hi(u6.x), w6, acc.x); acc.y = fmaf(bf16_hi(u6.y), w6, acc.y);
            acc.x = fmaf(bf16_hi(u7.x), w7, acc.x); acc.y = fmaf(bf16_hi(u7.y), w7, acc.y);
        }
    }
    acc.x = fmaxf(acc.x * di, 0.0f);
    acc.y = fmaxf(acc.y * di, 0.0f);
    X[(size_t)node * 64 + t] = acc;
}

// ---------------------------------------------------------------------------
// Tiled fp32 GEMM:  C[i,j] = sum_k A[i*lda+k] * W[j*ldw+k]  (+bias[j]) (+=C) (relu)
// BF16OUT: epilogue casts to bf16 (packed 4B stores). Compute always fp32.
// ---------------------------------------------------------------------------

template <int BM, int BN, int BK, int TM, int TN, bool RELU, bool ACCUM, bool BIAS, bool BF16OUT>
__global__ __launch_bounds__((BM / TM) * (BN / TN))
void gemm_kernel(const float* __restrict__ A, int lda,
                 const float* __restrict__ W, int ldw,
                 const float* __restrict__ bias,
                 void* __restrict__ Cv, int ldc,
                 int M, int K) {
    constexpr int THREADS = (BM / TM) * (BN / TN);
    __shared__ float As[BK][BM + 4];
    __shared__ float Ws[BK][BN + 4];

    int tid = threadIdx.x;
    int tcol = tid % (BN / TN);
    int trow = tid / (BN / TN);
    int rowBase = blockIdx.x * BM;
    int colBase = blockIdx.y * BN;

    float acc[TM][TN];
#pragma unroll
    for (int i = 0; i < TM; ++i)
#pragma unroll
        for (int j = 0; j < TN; ++j) acc[i][j] = 0.0f;

    for (int k0 = 0; k0 < K; k0 += BK) {
        constexpr int A_F4 = BM * BK / 4;
#pragma unroll
        for (int i = tid; i < A_F4; i += THREADS) {
            int m = i / (BK / 4);
            int kq = (i % (BK / 4)) * 4;
            int gr = rowBase + m;
            float4 v = make_float4(0.f, 0.f, 0.f, 0.f);
            if (gr < M) v = *(const float4*)(A + (size_t)gr * lda + k0 + kq);
            As[kq + 0][m] = v.x;
            As[kq + 1][m] = v.y;
            As[kq + 2][m] = v.z;
            As[kq + 3][m] = v.w;
        }
        constexpr int W_F4 = BN * BK / 4;
#pragma unroll
        for (int i = tid; i < W_F4; i += THREADS) {
            int n = i / (BK / 4);
            int kq = (i % (BK / 4)) * 4;
            float4 v = *(const float4*)(W + (size_t)(colBase + n) * ldw + k0 + kq);
            Ws[kq + 0][n] = v.x;
            Ws[kq + 1][n] = v.y;
            Ws[kq + 2][n] = v.z;
            Ws[kq + 3][n] = v.w;
        }
        __syncthreads();

#pragma unroll
        for (int kk = 0; kk < BK; ++kk) {
            float a[TM], w[TN];
#pragma unroll
            for (int i = 0; i < TM; ++i) a[i] = As[kk][trow * TM + i];
#pragma unroll
            for (int j = 0; j < TN; ++j) w[j] = Ws[kk][tcol * TN + j];
#pragma unroll
            for (int i = 0; i < TM; ++i)
#pragma unroll
                for (int j = 0; j < TN; ++j) acc[i][j] = fmaf(a[i], w[j], acc[i][j]);
        }
        __syncthreads();
    }

#pragma unroll
    for (int i = 0; i < TM; ++i) {
        int r = rowBase + trow * TM + i;
        if (r < M) {
#pragma unroll
            for (int j = 0; j < TN; ++j) {
                float v = acc[i][j];
                if (BIAS) v += bias[colBase + tcol * TN + j];
                if (RELU) v = fmaxf(v, 0.0f);
                acc[i][j] = v;
            }
            if (BF16OUT) {
                __hip_bfloat16* C = (__hip_bfloat16*)Cv;
#pragma unroll
                for (int j = 0; j < TN; j += 2) {
                    int c = colBase + tcol * TN + j;
                    __hip_bfloat162 p;
                    p.x = __float2bfloat16(acc[i][j]);
                    p.y = __float2bfloat16(acc[i][j + 1]);
                    *(__hip_bfloat162*)(C + (size_t)r * ldc + c) = p;
                }
            } else {
                float* C = (float*)Cv;
#pragma unroll
                for (int j = 0; j < TN; ++j) {
                    int c = colBase + tcol * TN + j;
                    float v = acc[i][j];
                    if (ACCUM) v += C[(size_t)r * ldc + c];
                    C[(size_t)r * ldc + c] = v;
                }
            }
        }
    }
}

// ---------------------------------------------------------------------------
// launch
// ---------------------------------------------------------------------------

extern "C" void kernel_launch(void* const* d_in, const int* in_sizes, int n_in,
                              void* d_out, int out_size, void* d_ws, size_t ws_size,
                              hipStream_t stream) {
    const float* x     = (const float*)d_in[0];
    const int*   ei    = (const int*)d_in[1];
    const float* W_in  = (const float*)d_in[2];
    const float* b_in  = (const float*)d_in[3];
    const float* Wc    = (const float*)d_in[4];
    const float* bc    = (const float*)d_in[5];
    const float* W_out = (const float*)d_in[6];
    const float* b_out = (const float*)d_in[7];
    float* out = (float*)d_out;

    const int HID = 128;
    const int N = in_sizes[0] / HID;   // 50000
    const int E = in_sizes[1] / 2;     // 800000
    const int L = 4;
    const int* src = ei;
    const int* dst = ei + E;

    char* ws = (char*)d_ws;
    size_t off = 0;
    auto carve = [&](size_t bytes) {
        void* p = ws + off;
        off += (bytes + 255) & ~(size_t)255;
        return p;
    };
    float* dinv      = (float*)carve((size_t)N * 4);
    int*   cnt       = (int*)carve((size_t)N * 4);
    int*   rowptr    = (int*)carve((size_t)(N + 1) * 4);
    int*   cursor    = (int*)carve((size_t)N * 4);
    int*   csr_src   = (int*)carve((size_t)E * 4);
    float* bufA      = (float*)carve((size_t)N * HID * 4);          // fp32 activations
    __hip_bfloat16* bufHb = (__hip_bfloat16*)carve((size_t)N * HID * 2);  // bf16 pre-agg
    int*   blockSums = (int*)carve((size_t)1024 * 4);
    int*   blockOffs = (int*)carve((size_t)1024 * 4);
    (void)ws_size;

    // ---- CSR + norm build ----
    hipMemsetAsync(cnt, 0, (size_t)N * 4, stream);
    count_kernel<<<(E + 255) / 256, 256, 0, stream>>>(dst, E, cnt);
    dinv_kernel<<<(N + 255) / 256, 256, 0, stream>>>(cnt, dinv, N);
    int B = (N + 1023) / 1024;
    scan_phase1<<<B, 256, 0, stream>>>(cnt, N, blockSums);
    scan_phase2<<<1, 1024, 0, stream>>>(blockSums, blockOffs, B);
    scan_phase3<<<B, 256, 0, stream>>>(cnt, blockOffs, rowptr, cursor, N, E);
    fill_kernel<<<(E + 255) / 256, 256, 0, stream>>>(src, dst, E, cursor, csr_src);

    dim3 gemm_grid((N + 127) / 128, 1);

    // ---- input projection: bufA = relu(x @ W_in^T + b_in)  [fp32 out] ----
    gemm_kernel<128, 128, 16, 8, 8, true, false, true, false>
        <<<gemm_grid, 256, 0, stream>>>(x, HID, W_in, HID, b_in, bufA, HID, N, HID);

    // ---- conv layers ----
    for (int l = 0; l < L; ++l) {
        // bufHb = bf16( bufA @ Wc[l]^T + bc[l] )
        gemm_kernel<128, 128, 16, 8, 8, false, false, true, true>
            <<<gemm_grid, 256, 0, stream>>>(bufA, HID, Wc + (size_t)l * HID * HID, HID,
                                            bc + (size_t)l * HID, bufHb, HID, N, HID);
        // bufA = relu(aggregate(bufHb))  [fp32 out]
        agg_kernel<<<(N + 3) / 4, 256, 0, stream>>>((const ushort2*)bufHb, dinv, rowptr,
                                                    csr_src, (float2*)bufA, N);
        // out (+)= bufA @ W_out[:, l*128:(l+1)*128]^T  (+ b_out at l==0)
        if (l == 0) {
            gemm_kernel<128, 64, 32, 8, 4, false, false, true, false>
                <<<gemm_grid, 256, 0, stream>>>(bufA, HID, W_out + (size_t)l * HID, 512,
                                                b_out, out, 64, N, HID);
        } else {
            gemm_kernel<128, 64, 32, 8, 4, false, true, false, false>
                <<<gemm_grid, 256, 0, stream>>>(bufA, HID, W_out + (size_t)l * HID, 512,
                                                nullptr, out, 64, N, HID);
        }
    }
}

// Round 5
// 433.270 us; speedup vs baseline: 1.9970x; 1.2380x over previous
//
#include <hip/hip_runtime.h>
#include <hip/hip_bf16.h>

#ifndef MIN
#define MIN(a,b) ((a)<(b)?(a):(b))
#endif

typedef _Float16 half2_t __attribute__((ext_vector_type(2)));
typedef _Float16 half4_t __attribute__((ext_vector_type(4)));
typedef _Float16 half8_t __attribute__((ext_vector_type(8)));
typedef float floatx4 __attribute__((ext_vector_type(4)));

// ---------------------------------------------------------------------------
// CSR build kernels
// ---------------------------------------------------------------------------

__global__ void count_kernel(const int* __restrict__ dst, int E, int* __restrict__ cnt) {
    int e = blockIdx.x * blockDim.x + threadIdx.x;
    if (e < E) atomicAdd(&cnt[dst[e]], 1);
}

__global__ void dinv_kernel(const int* __restrict__ cnt, float* __restrict__ dinv, int N) {
    int i = blockIdx.x * blockDim.x + threadIdx.x;
    if (i < N) dinv[i] = rsqrtf((float)(cnt[i] + 1));   // self loop -> deg >= 1
}

__global__ void scan_phase1(const int* __restrict__ cnt, int N, int* __restrict__ blockSums) {
    int b = blockIdx.x;
    int t = threadIdx.x;
    int base = b * 1024 + t * 4;
    int s = 0;
#pragma unroll
    for (int k = 0; k < 4; ++k) {
        int i = base + k;
        if (i < N) s += cnt[i];
    }
    __shared__ int sm[256];
    sm[t] = s;
    __syncthreads();
    for (int off = 128; off > 0; off >>= 1) {
        if (t < off) sm[t] += sm[t + off];
        __syncthreads();
    }
    if (t == 0) blockSums[b] = sm[0];
}

__global__ void scan_phase2(const int* __restrict__ blockSums, int* __restrict__ blockOffsets, int B) {
    __shared__ int sm[1024];
    int t = threadIdx.x;
    int v = (t < B) ? blockSums[t] : 0;
    sm[t] = v;
    __syncthreads();
    for (int off = 1; off < 1024; off <<= 1) {
        int add = (t >= off) ? sm[t - off] : 0;
        __syncthreads();
        sm[t] += add;
        __syncthreads();
    }
    if (t < B) blockOffsets[t] = sm[t] - v;   // exclusive
}

__global__ void scan_phase3(const int* __restrict__ cnt, const int* __restrict__ blockOffsets,
                            int* __restrict__ rowptr, int* __restrict__ cursor, int N, int E) {
    int b = blockIdx.x;
    int t = threadIdx.x;
    int base = b * 1024 + t * 4;
    int v[4];
    int s = 0;
#pragma unroll
    for (int k = 0; k < 4; ++k) {
        int i = base + k;
        v[k] = (i < N) ? cnt[i] : 0;
        s += v[k];
    }
    __shared__ int sm[256];
    sm[t] = s;
    __syncthreads();
    for (int off = 1; off < 256; off <<= 1) {
        int add = (t >= off) ? sm[t - off] : 0;
        __syncthreads();
        sm[t] += add;
        __syncthreads();
    }
    int excl = sm[t] - s + blockOffsets[b];
#pragma unroll
    for (int k = 0; k < 4; ++k) {
        int i = base + k;
        if (i < N) {
            rowptr[i] = excl;
            cursor[i] = excl;
            excl += v[k];
        }
    }
    if (b == 0 && t == 0) rowptr[N] = E;
}

__global__ void fill_kernel(const int* __restrict__ src, const int* __restrict__ dst,
                            int E, int* __restrict__ cursor, int* __restrict__ csr_src) {
    int e = blockIdx.x * blockDim.x + threadIdx.x;
    if (e < E) {
        int d = dst[e];
        int pos = atomicAdd(&cursor[d], 1);
        csr_src[pos] = src[e];
    }
}

// ---------------------------------------------------------------------------
// Weight fp32 -> f16 conversion (once per call; 3 arrays in one launch)
// ---------------------------------------------------------------------------

__global__ void cvt_weights(const float* __restrict__ a, _Float16* __restrict__ oa, int na,
                            const float* __restrict__ b, _Float16* __restrict__ ob, int nb,
                            const float* __restrict__ c, _Float16* __restrict__ oc, int nc) {
    int i = blockIdx.x * blockDim.x + threadIdx.x;
    if (i < na) oa[i] = (_Float16)a[i];
    if (i < nb) ob[i] = (_Float16)b[i];
    if (i < nc) oc[i] = (_Float16)c[i];
}

// ---------------------------------------------------------------------------
// Aggregation over f16 H: X[node] = relu( di*( di*H[node] + sum dinv[s]*H[s] ) )
// 1 wave per node, 1 dword (2 f16 ch) per lane; 64-edge batches via shfl,
// 8 independent row gathers in flight. Accumulate fp32; X written f16.
// ---------------------------------------------------------------------------

__global__ void agg_kernel(const half2_t* __restrict__ Hb, const float* __restrict__ dinv,
                           const int* __restrict__ rowptr, const int* __restrict__ csr_src,
                           half2_t* __restrict__ X, int N) {
    int node = blockIdx.x * 4 + (threadIdx.x >> 6);
    int t = threadIdx.x & 63;
    if (node >= N) return;
    float di = dinv[node];
    half2_t hu = Hb[(size_t)node * 64 + t];
    float2 acc;
    acc.x = (float)hu.x * di;
    acc.y = (float)hu.y * di;
    int beg = rowptr[node];
    int end = rowptr[node + 1];

    for (int base = beg; base < end; base += 64) {
        int idx = base + t;
        bool valid = idx < end;
        int s_lane = valid ? csr_src[idx] : node;    // safe address for pads
        float w_lane = valid ? dinv[s_lane] : 0.0f;  // zero weight for pads
        int m = end - base;
        if (m > 64) m = 64;
        int mm = (m + 7) & ~7;                       // pads contribute 0
        for (int j = 0; j < mm; j += 8) {
            int s0 = __shfl(s_lane, j + 0), s1 = __shfl(s_lane, j + 1);
            int s2 = __shfl(s_lane, j + 2), s3 = __shfl(s_lane, j + 3);
            int s4 = __shfl(s_lane, j + 4), s5 = __shfl(s_lane, j + 5);
            int s6 = __shfl(s_lane, j + 6), s7 = __shfl(s_lane, j + 7);
            float w0 = __shfl(w_lane, j + 0), w1 = __shfl(w_lane, j + 1);
            float w2 = __shfl(w_lane, j + 2), w3 = __shfl(w_lane, j + 3);
            float w4 = __shfl(w_lane, j + 4), w5 = __shfl(w_lane, j + 5);
            float w6 = __shfl(w_lane, j + 6), w7 = __shfl(w_lane, j + 7);
            half2_t u0 = Hb[(size_t)s0 * 64 + t];
            half2_t u1 = Hb[(size_t)s1 * 64 + t];
            half2_t u2 = Hb[(size_t)s2 * 64 + t];
            half2_t u3 = Hb[(size_t)s3 * 64 + t];
            half2_t u4 = Hb[(size_t)s4 * 64 + t];
            half2_t u5 = Hb[(size_t)s5 * 64 + t];
            half2_t u6 = Hb[(size_t)s6 * 64 + t];
            half2_t u7 = Hb[(size_t)s7 * 64 + t];
            acc.x = fmaf((float)u0.x, w0, acc.x); acc.y = fmaf((float)u0.y, w0, acc.y);
            acc.x = fmaf((float)u1.x, w1, acc.x); acc.y = fmaf((float)u1.y, w1, acc.y);
            acc.x = fmaf((float)u2.x, w2, acc.x); acc.y = fmaf((float)u2.y, w2, acc.y);
            acc.x = fmaf((float)u3.x, w3, acc.x); acc.y = fmaf((float)u3.y, w3, acc.y);
            acc.x = fmaf((float)u4.x, w4, acc.x); acc.y = fmaf((float)u4.y, w4, acc.y);
            acc.x = fmaf((float)u5.x, w5, acc.x); acc.y = fmaf((float)u5.y, w5, acc.y);
            acc.x = fmaf((float)u6.x, w6, acc.x); acc.y = fmaf((float)u6.y, w6, acc.y);
            acc.x = fmaf((float)u7.x, w7, acc.x); acc.y = fmaf((float)u7.y, w7, acc.y);
        }
    }
    half2_t o;
    o.x = (_Float16)fmaxf(acc.x * di, 0.0f);
    o.y = (_Float16)fmaxf(acc.y * di, 0.0f);
    X[(size_t)node * 64 + t] = o;
}

// ---------------------------------------------------------------------------
// MFMA f16 GEMM, K=128 fixed, BM=64, 256 threads (4 waves, 16 rows/wave).
// C[m][n] = sum_k A[m][k] * W[n][k]  (+bias[n]) (relu) -> f16 or fp32(+=) out.
// Fragment layout (verified m89/m91/m120): A/B lane reads row=lane&15,
// k=(lane>>4)*8..+7 ; C/D col=lane&15, row=(lane>>4)*4+reg.
// ---------------------------------------------------------------------------

template <int BN, bool A_F16, bool RELU, bool BIAS, bool ACCUM, bool F16OUT>
__global__ __launch_bounds__(256)
void mfma_gemm(const void* __restrict__ Av,
               const _Float16* __restrict__ W, int ldw,
               const float* __restrict__ bias,
               void* __restrict__ Cv, int ldc, int M) {
    constexpr int NT = BN / 16;
    __shared__ __align__(16) _Float16 As[64][136];
    __shared__ __align__(16) _Float16 Ws[BN][136];

    int tid = threadIdx.x;
    int rowBase = blockIdx.x * 64;

    // ---- stage W (f16, pre-converted) ----
#pragma unroll
    for (int i = tid; i < BN * 16; i += 256) {
        int n = i >> 4, k8 = (i & 15) * 8;
        uint4 v = *(const uint4*)(W + (size_t)n * ldw + k8);
        *(uint4*)(&Ws[n][k8]) = v;
    }
    // ---- stage A ----
    if (A_F16) {
        const _Float16* A = (const _Float16*)Av;
#pragma unroll
        for (int i = tid; i < 64 * 16; i += 256) {
            int r = i >> 4, k8 = (i & 15) * 8;
            int gr = rowBase + r;
            uint4 v = make_uint4(0, 0, 0, 0);
            if (gr < M) v = *(const uint4*)(A + (size_t)gr * 128 + k8);
            *(uint4*)(&As[r][k8]) = v;
        }
    } else {
        const float* A = (const float*)Av;
#pragma unroll
        for (int i = tid; i < 64 * 32; i += 256) {
            int r = i >> 5, c4 = (i & 31) * 4;
            int gr = rowBase + r;
            half4_t h = {0, 0, 0, 0};
            if (gr < M) {
                float4 v = *(const float4*)(A + (size_t)gr * 128 + c4);
                h.x = (_Float16)v.x; h.y = (_Float16)v.y;
                h.z = (_Float16)v.z; h.w = (_Float16)v.w;
            }
            *(half4_t*)(&As[r][c4]) = h;
        }
    }
    __syncthreads();

    // ---- compute ----
    int w = tid >> 6;          // wave id: rows w*16..w*16+15
    int lane = tid & 63;
    int lrow = lane & 15;
    int kq = (lane >> 4) * 8;

    floatx4 acc[NT];
#pragma unroll
    for (int nt = 0; nt < NT; ++nt) acc[nt] = (floatx4){0.f, 0.f, 0.f, 0.f};

#pragma unroll
    for (int ks = 0; ks < 4; ++ks) {
        int kk = ks * 32 + kq;
        half8_t a = *(const half8_t*)(&As[w * 16 + lrow][kk]);
#pragma unroll
        for (int nt = 0; nt < NT; ++nt) {
            half8_t b = *(const half8_t*)(&Ws[nt * 16 + lrow][kk]);
            acc[nt] = __builtin_amdgcn_mfma_f32_16x16x32_f16(a, b, acc[nt], 0, 0, 0);
        }
    }

    // ---- epilogue ----
    int quad = lane >> 4;
#pragma unroll
    for (int nt = 0; nt < NT; ++nt) {
        int col = nt * 16 + lrow;
        float bv = BIAS ? bias[col] : 0.0f;
#pragma unroll
        for (int reg = 0; reg < 4; ++reg) {
            int gr = rowBase + w * 16 + quad * 4 + reg;
            if (gr < M) {
                float v = acc[nt][reg] + bv;
                if (RELU) v = fmaxf(v, 0.0f);
                if (F16OUT) {
                    _Float16* C = (_Float16*)Cv;
                    C[(size_t)gr * ldc + col] = (_Float16)v;
                } else {
                    float* C = (float*)Cv;
                    if (ACCUM) v += C[(size_t)gr * ldc + col];
                    C[(size_t)gr * ldc + col] = v;
                }
            }
        }
    }
}

// ---------------------------------------------------------------------------
// launch
// ---------------------------------------------------------------------------

extern "C" void kernel_launch(void* const* d_in, const int* in_sizes, int n_in,
                              void* d_out, int out_size, void* d_ws, size_t ws_size,
                              hipStream_t stream) {
    const float* x     = (const float*)d_in[0];
    const int*   ei    = (const int*)d_in[1];
    const float* W_in  = (const float*)d_in[2];
    const float* b_in  = (const float*)d_in[3];
    const float* Wc    = (const float*)d_in[4];
    const float* bc    = (const float*)d_in[5];
    const float* W_out = (const float*)d_in[6];
    const float* b_out = (const float*)d_in[7];
    float* out = (float*)d_out;

    const int HID = 128;
    const int N = in_sizes[0] / HID;   // 50000
    const int E = in_sizes[1] / 2;     // 800000
    const int L = 4;
    const int* src = ei;
    const int* dst = ei + E;

    char* ws = (char*)d_ws;
    size_t off = 0;
    auto carve = [&](size_t bytes) {
        void* p = ws + off;
        off += (bytes + 255) & ~(size_t)255;
        return p;
    };
    float* dinv      = (float*)carve((size_t)N * 4);
    int*   cnt       = (int*)carve((size_t)N * 4);
    int*   rowptr    = (int*)carve((size_t)(N + 1) * 4);
    int*   cursor    = (int*)carve((size_t)N * 4);
    int*   csr_src   = (int*)carve((size_t)E * 4);
    _Float16* bufA   = (_Float16*)carve((size_t)N * HID * 2);   // f16 activations
    _Float16* bufH   = (_Float16*)carve((size_t)N * HID * 2);   // f16 pre-agg
    _Float16* Wf_in  = (_Float16*)carve((size_t)HID * HID * 2);
    _Float16* Wf_c   = (_Float16*)carve((size_t)L * HID * HID * 2);
    _Float16* Wf_out = (_Float16*)carve((size_t)64 * 512 * 2);
    int*   blockSums = (int*)carve((size_t)1024 * 4);
    int*   blockOffs = (int*)carve((size_t)1024 * 4);
    (void)ws_size;

    // ---- CSR + norm build ----
    hipMemsetAsync(cnt, 0, (size_t)N * 4, stream);
    count_kernel<<<(E + 255) / 256, 256, 0, stream>>>(dst, E, cnt);
    dinv_kernel<<<(N + 255) / 256, 256, 0, stream>>>(cnt, dinv, N);
    int B = (N + 1023) / 1024;
    scan_phase1<<<B, 256, 0, stream>>>(cnt, N, blockSums);
    scan_phase2<<<1, 1024, 0, stream>>>(blockSums, blockOffs, B);
    scan_phase3<<<B, 256, 0, stream>>>(cnt, blockOffs, rowptr, cursor, N, E);
    fill_kernel<<<(E + 255) / 256, 256, 0, stream>>>(src, dst, E, cursor, csr_src);

    // ---- weights -> f16 ----
    cvt_weights<<<(L * HID * HID + 255) / 256, 256, 0, stream>>>(
        W_in, Wf_in, HID * HID,
        Wc, Wf_c, L * HID * HID,
        W_out, Wf_out, 64 * 512);

    int gemm_blocks = (N + 63) / 64;

    // ---- input projection: bufA = f16( relu(x @ W_in^T + b_in) ) ----
    mfma_gemm<128, false, true, true, false, true>
        <<<gemm_blocks, 256, 0, stream>>>(x, Wf_in, HID, b_in, bufA, HID, N);

    // ---- conv layers ----
    for (int l = 0; l < L; ++l) {
        // bufH = f16( bufA @ Wc[l]^T + bc[l] )
        mfma_gemm<128, true, false, true, false, true>
            <<<gemm_blocks, 256, 0, stream>>>(bufA, Wf_c + (size_t)l * HID * HID, HID,
                                              bc + (size_t)l * HID, bufH, HID, N);
        // bufA = f16( relu(aggregate(bufH)) )
        agg_kernel<<<(N + 3) / 4, 256, 0, stream>>>((const half2_t*)bufH, dinv, rowptr,
                                                    csr_src, (half2_t*)bufA, N);
        // out (+)= bufA @ W_out[:, l*128:(l+1)*128]^T  (+ b_out at l==0)
        if (l == 0) {
            mfma_gemm<64, true, false, true, false, false>
                <<<gemm_blocks, 256, 0, stream>>>(bufA, Wf_out + (size_t)l * HID, 512,
                                                  b_out, out, 64, N);
        } else {
            mfma_gemm<64, true, false, false, true, false>
                <<<gemm_blocks, 256, 0, stream>>>(bufA, Wf_out + (size_t)l * HID, 512,
                                                  nullptr, out, 64, N);
        }
    }
}